// Round 3
// baseline (41.290 us; speedup 1.0000x reference)
//
#include <hip/hip_runtime.h>
#include <hip/hip_bf16.h>

#define NS   256
#define DIN  512
#define DHID 1024

typedef __attribute__((ext_vector_type(8))) short bf16x8;
typedef __attribute__((ext_vector_type(4))) float f32x4;

static __device__ __forceinline__ short f2bf(float f) {
    return __builtin_bit_cast(short, __float2bfloat16(f));   // RNE
}

static __device__ __forceinline__ bf16x8 cvt8(f32x4 a, f32x4 b) {
    bf16x8 r;
    r[0] = f2bf(a[0]); r[1] = f2bf(a[1]); r[2] = f2bf(a[2]); r[3] = f2bf(a[3]);
    r[4] = f2bf(b[0]); r[5] = f2bf(b[1]); r[6] = f2bf(b[2]); r[7] = f2bf(b[3]);
    return r;
}

// One kernel, two phases, device-scope barrier between.
// Phase 1 (feat): Z = [x1;x2] @ W1 + b1; Hb = relu(Z), Gb = (Z>0)*w2  (bf16, in ws)
//   block b: rows m0=(b>>4)*32, cols (b&15)*64; wave w owns 16-col strip, 32 rows.
//   B-fragment loaded DIRECTLY from row-major f32 W1 (strided scalar, coalesced
//   across the 16-lane col groups) -> no transpose/convert kernel needed.
// Phase 2 (gram): out[i][j] = (x1_i.x2_j + 1)*(g1_i.g2_j) + h1_i.h2_j + 1
//   block b: 16x16 tile bi=(b>>4)*16, bj=(b&15)*16; 4 waves K-split; LDS reduce.
__global__ __launch_bounds__(256) void ntk_fused(
    const float* __restrict__ x1, const float* __restrict__ x2,
    const float* __restrict__ W1, const float* __restrict__ b1,
    const float* __restrict__ w2,
    short* __restrict__ Hb, short* __restrict__ Gb,
    unsigned int* __restrict__ cnt,
    float* __restrict__ out)
{
    const int tid = threadIdx.x;
    const int l   = tid & 63;
    const int w   = tid >> 6;
    const int lr  = l & 15;
    const int kg  = l >> 4;
    const int b   = blockIdx.x;

    __shared__ f32x4 red[3][4][64];   // 12 KiB (phase 2)

    // ---------------- phase 1: features ----------------
    {
        const int m0  = (b >> 4) * 32;
        const int col = (b & 15) * 64 + w * 16 + lr;
        const float* X = (m0 < NS) ? (x1 + (size_t)m0 * DIN)
                                   : (x2 + (size_t)(m0 - NS) * DIN);
        const float* a0p = X + lr * DIN;
        const float* a1p = X + (lr + 16) * DIN;
        const float* bp  = W1 + (size_t)(kg * 8) * DHID + col;   // + (k+i)*DHID

        f32x4 acc0 = {0.f,0.f,0.f,0.f}, acc1 = {0.f,0.f,0.f,0.f};
        #pragma unroll 4
        for (int t = 0; t < 16; ++t) {
            const int k = t * 32 + kg * 8;
            bf16x8 a0 = cvt8(*(const f32x4*)(a0p + k), *(const f32x4*)(a0p + k + 4));
            bf16x8 a1 = cvt8(*(const f32x4*)(a1p + k), *(const f32x4*)(a1p + k + 4));
            f32x4 b0v, b1v;
            #pragma unroll
            for (int i = 0; i < 4; ++i) b0v[i] = bp[(size_t)(t * 32 + i) * DHID];
            #pragma unroll
            for (int i = 0; i < 4; ++i) b1v[i] = bp[(size_t)(t * 32 + 4 + i) * DHID];
            bf16x8 bf = cvt8(b0v, b1v);
            acc0 = __builtin_amdgcn_mfma_f32_16x16x32_bf16(a0, bf, acc0, 0, 0, 0);
            acc1 = __builtin_amdgcn_mfma_f32_16x16x32_bf16(a1, bf, acc1, 0, 0, 0);
        }

        const float bbv = b1[col], wwv = w2[col];
        #pragma unroll
        for (int r = 0; r < 4; ++r) {
            const int row = m0 + kg * 4 + r;           // D: col=l&15, row=(l>>4)*4+r
            float z0 = acc0[r] + bbv;
            float z1 = acc1[r] + bbv;
            Hb[row * DHID + col]        = f2bf(z0 > 0.f ? z0  : 0.f);
            Gb[row * DHID + col]        = f2bf(z0 > 0.f ? wwv : 0.f);
            Hb[(row + 16) * DHID + col] = f2bf(z1 > 0.f ? z1  : 0.f);
            Gb[(row + 16) * DHID + col] = f2bf(z1 > 0.f ? wwv : 0.f);
        }
    }

    // ---------------- device-scope barrier ----------------
    __syncthreads();                       // drains this block's Hb/Gb stores (vmcnt)
    if (tid == 0) {
        // release: write back this XCD's L2 (covers whole block's stores), then signal
        __hip_atomic_fetch_add(cnt, 1u, __ATOMIC_RELEASE, __HIP_MEMORY_SCOPE_AGENT);
        while (__hip_atomic_load(cnt, __ATOMIC_RELAXED, __HIP_MEMORY_SCOPE_AGENT) < 256u)
            __builtin_amdgcn_s_sleep(1);
        __threadfence();                   // acquire: invalidate this CU's caches
    }
    __syncthreads();

    // ---------------- phase 2: gram + combine ----------------
    {
        const int bi = (b >> 4) * 16;
        const int bj = (b & 15) * 16;

        f32x4 ac = {0.f,0.f,0.f,0.f}, ag = {0.f,0.f,0.f,0.f}, ah = {0.f,0.f,0.f,0.f};

        // c = x1 . x2 (16 ksteps, 4 per wave)
        const float* ar = x1 + (bi + lr) * DIN + kg * 8;
        const float* br = x2 + (bj + lr) * DIN + kg * 8;
        #pragma unroll
        for (int t = 0; t < 4; ++t) {
            const int k = (w + t * 4) * 32;
            bf16x8 a = cvt8(*(const f32x4*)(ar + k), *(const f32x4*)(ar + k + 4));
            bf16x8 bb = cvt8(*(const f32x4*)(br + k), *(const f32x4*)(br + k + 4));
            ac = __builtin_amdgcn_mfma_f32_16x16x32_bf16(a, bb, ac, 0, 0, 0);
        }
        // g = g1 . g2 (32 ksteps, 8 per wave)
        const short* ga = Gb + (bi + lr) * DHID + kg * 8;
        const short* gb = Gb + (NS + bj + lr) * DHID + kg * 8;
        #pragma unroll
        for (int t = 0; t < 8; ++t) {
            const int k = (w + t * 4) * 32;
            bf16x8 a  = *(const bf16x8*)(ga + k);
            bf16x8 bb = *(const bf16x8*)(gb + k);
            ag = __builtin_amdgcn_mfma_f32_16x16x32_bf16(a, bb, ag, 0, 0, 0);
        }
        // h = h1 . h2 (32 ksteps, 8 per wave)
        const short* ha = Hb + (bi + lr) * DHID + kg * 8;
        const short* hb = Hb + (NS + bj + lr) * DHID + kg * 8;
        #pragma unroll
        for (int t = 0; t < 8; ++t) {
            const int k = (w + t * 4) * 32;
            bf16x8 a  = *(const bf16x8*)(ha + k);
            bf16x8 bb = *(const bf16x8*)(hb + k);
            ah = __builtin_amdgcn_mfma_f32_16x16x32_bf16(a, bb, ah, 0, 0, 0);
        }

        red[0][w][l] = ac; red[1][w][l] = ag; red[2][w][l] = ah;
        __syncthreads();
        if (w == 0) {
            f32x4 c = red[0][0][l], g = red[1][0][l], h = red[2][0][l];
            #pragma unroll
            for (int q = 1; q < 4; ++q) { c += red[0][q][l]; g += red[1][q][l]; h += red[2][q][l]; }
            #pragma unroll
            for (int r = 0; r < 4; ++r)
                out[(bi + kg * 4 + r) * NS + (bj + lr)] = (c[r] + 1.f) * g[r] + h[r] + 1.f;
        }
    }
}

extern "C" void kernel_launch(void* const* d_in, const int* in_sizes, int n_in,
                              void* d_out, int out_size, void* d_ws, size_t ws_size,
                              hipStream_t stream) {
    const float* x1 = (const float*)d_in[0];   // [256,512]
    const float* x2 = (const float*)d_in[1];   // [256,512]
    const float* W1 = (const float*)d_in[2];   // [512,1024]
    const float* b1 = (const float*)d_in[3];   // [1024]
    const float* w2 = (const float*)d_in[4];   // [1024,1]
    // d_in[5] = b2: d f / d b2 == 1 always -> the "+1" term.

    short* Hb = (short*)d_ws;                          // [512,1024] bf16, 1 MiB
    short* Gb = Hb + 2 * NS * DHID;                    // [512,1024] bf16, 1 MiB
    unsigned int* cnt = (unsigned int*)((char*)d_ws + 2 * NS * DHID * 2 * sizeof(short));
    float* out = (float*)d_out;                        // [256,256]

    (void)hipMemsetAsync(cnt, 0, sizeof(unsigned int), stream);  // barrier counter = 0
    ntk_fused<<<256, 256, 0, stream>>>(x1, x2, W1, b1, w2, Hb, Gb, cnt, out);
}

// Round 4
// 24.430 us; speedup vs baseline: 1.6901x; 1.6901x over previous
//
#include <hip/hip_runtime.h>
#include <hip/hip_bf16.h>

#define NS   256
#define DIN  512
#define DHID 1024

typedef __attribute__((ext_vector_type(8))) short bf16x8;
typedef __attribute__((ext_vector_type(4))) float f32x4;

static __device__ __forceinline__ short f2bf(float f) {
    return __builtin_bit_cast(short, __float2bfloat16(f));   // RNE
}

static __device__ __forceinline__ bf16x8 cvt8(f32x4 a, f32x4 b) {
    bf16x8 r;
    r[0] = f2bf(a[0]); r[1] = f2bf(a[1]); r[2] = f2bf(a[2]); r[3] = f2bf(a[3]);
    r[4] = f2bf(b[0]); r[5] = f2bf(b[1]); r[6] = f2bf(b[2]); r[7] = f2bf(b[3]);
    return r;
}

// ---------------- K1: heterogeneous, 768 blocks (3/CU) ----------------
// blocks 0..511  : feat tile 16 rows x 64 cols. Z = X@W1+b1; Hb=relu, Gb=(Z>0)*w2.
//                  W1 read directly (f32, strided scalar B-frag loads; 3 waves/SIMD
//                  TLP hides the latency -- r3's version of this ran at 1 wave/SIMD).
// blocks 512..767: c-gram 16x16 tile of x1.x2^T -> Cws (f32), 4-wave K-split.
__global__ __launch_bounds__(256, 3) void ntk_k1(
    const float* __restrict__ x1, const float* __restrict__ x2,
    const float* __restrict__ W1, const float* __restrict__ b1,
    const float* __restrict__ w2,
    short* __restrict__ Hb, short* __restrict__ Gb,
    float* __restrict__ Cws)
{
    const int tid = threadIdx.x;
    const int l   = tid & 63;
    const int w   = tid >> 6;
    const int lr  = l & 15;
    const int kg  = l >> 4;
    const int b   = blockIdx.x;

    if (b < 512) {
        // ---------- feature pass ----------
        const int m0  = (b >> 4) * 16;                 // row tile (0..496)
        const int col = (b & 15) * 64 + w * 16 + lr;   // output column
        const float* X = (m0 < NS) ? (x1 + (size_t)m0 * DIN)
                                   : (x2 + (size_t)(m0 - NS) * DIN);
        const float* ap = X + lr * DIN;                // A row for this lane
        const float* bp = W1 + (size_t)(kg * 8) * DHID + col;

        f32x4 acc = {0.f, 0.f, 0.f, 0.f};
        #pragma unroll 4
        for (int t = 0; t < 16; ++t) {
            const int k = t * 32 + kg * 8;
            bf16x8 a = cvt8(*(const f32x4*)(ap + k), *(const f32x4*)(ap + k + 4));
            f32x4 b0v, b1v;
            #pragma unroll
            for (int i = 0; i < 4; ++i) b0v[i] = bp[(size_t)(t * 32 + i) * DHID];
            #pragma unroll
            for (int i = 0; i < 4; ++i) b1v[i] = bp[(size_t)(t * 32 + 4 + i) * DHID];
            bf16x8 bf = cvt8(b0v, b1v);
            acc = __builtin_amdgcn_mfma_f32_16x16x32_bf16(a, bf, acc, 0, 0, 0);
        }

        const float bbv = b1[col], wwv = w2[col];
        #pragma unroll
        for (int r = 0; r < 4; ++r) {                  // D: col=l&15, row=(l>>4)*4+r
            const int row = m0 + kg * 4 + r;
            float z = acc[r] + bbv;
            Hb[row * DHID + col] = f2bf(z > 0.f ? z   : 0.f);
            Gb[row * DHID + col] = f2bf(z > 0.f ? wwv : 0.f);
        }
    } else {
        // ---------- c = x1 . x2^T ----------
        __shared__ f32x4 red[4][64];                   // 4 KiB
        const int bb = b - 512;
        const int bi = (bb >> 4) * 16;
        const int bj = (bb & 15) * 16;

        const float* ar = x1 + (bi + lr) * DIN + kg * 8;
        const float* br = x2 + (bj + lr) * DIN + kg * 8;
        f32x4 ac = {0.f, 0.f, 0.f, 0.f};
        #pragma unroll
        for (int t = 0; t < 4; ++t) {
            const int k = (w + t * 4) * 32;
            bf16x8 a  = cvt8(*(const f32x4*)(ar + k), *(const f32x4*)(ar + k + 4));
            bf16x8 bv = cvt8(*(const f32x4*)(br + k), *(const f32x4*)(br + k + 4));
            ac = __builtin_amdgcn_mfma_f32_16x16x32_bf16(a, bv, ac, 0, 0, 0);
        }
        red[w][l] = ac;
        __syncthreads();
        if (w == 0) {
            f32x4 c = red[0][l];
            #pragma unroll
            for (int q = 1; q < 4; ++q) c += red[q][l];
            #pragma unroll
            for (int r = 0; r < 4; ++r)
                Cws[(bi + kg * 4 + r) * NS + (bj + lr)] = c[r];
        }
    }
}

// ---------------- K2: g/h grams + combine. 256 blocks x 512 thr (2 waves/SIMD) ----
// out[i][j] = (c + 1) * (g1_i.g2_j) + h1_i.h2_j + 1
__global__ __launch_bounds__(512) void ntk_k2(
    const short* __restrict__ Hb, const short* __restrict__ Gb,
    const float* __restrict__ Cws, float* __restrict__ out)
{
    const int tid = threadIdx.x;
    const int l   = tid & 63;
    const int w   = tid >> 6;          // 0..7
    const int lr  = l & 15;
    const int kg  = l >> 4;
    const int bi  = (blockIdx.x >> 4) * 16;
    const int bj  = (blockIdx.x & 15) * 16;

    __shared__ f32x4 red[2][8][64];    // 16 KiB

    f32x4 ag = {0.f,0.f,0.f,0.f}, ah = {0.f,0.f,0.f,0.f};

    const short* ga = Gb + (bi + lr) * DHID + kg * 8;
    const short* gb = Gb + (NS + bj + lr) * DHID + kg * 8;
    const short* ha = Hb + (bi + lr) * DHID + kg * 8;
    const short* hb = Hb + (NS + bj + lr) * DHID + kg * 8;

    #pragma unroll
    for (int t = 0; t < 4; ++t) {      // 32 ksteps, 8-way wave split
        const int k = (w + t * 8) * 32;
        bf16x8 a  = *(const bf16x8*)(ga + k);
        bf16x8 bv = *(const bf16x8*)(gb + k);
        ag = __builtin_amdgcn_mfma_f32_16x16x32_bf16(a, bv, ag, 0, 0, 0);
        bf16x8 a2 = *(const bf16x8*)(ha + k);
        bf16x8 b2 = *(const bf16x8*)(hb + k);
        ah = __builtin_amdgcn_mfma_f32_16x16x32_bf16(a2, b2, ah, 0, 0, 0);
    }

    red[0][w][l] = ag; red[1][w][l] = ah;
    __syncthreads();
    if (w == 0) {
        f32x4 g = red[0][0][l], h = red[1][0][l];
        #pragma unroll
        for (int q = 1; q < 8; ++q) { g += red[0][q][l]; h += red[1][q][l]; }
        #pragma unroll
        for (int r = 0; r < 4; ++r) {
            const int idx = (bi + kg * 4 + r) * NS + (bj + lr);
            out[idx] = (Cws[idx] + 1.f) * g[r] + h[r] + 1.f;
        }
    }
}

extern "C" void kernel_launch(void* const* d_in, const int* in_sizes, int n_in,
                              void* d_out, int out_size, void* d_ws, size_t ws_size,
                              hipStream_t stream) {
    const float* x1 = (const float*)d_in[0];   // [256,512]
    const float* x2 = (const float*)d_in[1];   // [256,512]
    const float* W1 = (const float*)d_in[2];   // [512,1024]
    const float* b1 = (const float*)d_in[3];   // [1024]
    const float* w2 = (const float*)d_in[4];   // [1024,1]
    // d_in[5] = b2: d f / d b2 == 1 always -> the "+1" term.

    short* Hb  = (short*)d_ws;                 // [512,1024] bf16, 1 MiB
    short* Gb  = Hb + 2 * NS * DHID;           // [512,1024] bf16, 1 MiB
    float* Cws = (float*)(Gb + 2 * NS * DHID); // [256,256]  f32, 256 KiB
    float* out = (float*)d_out;                // [256,256]

    ntk_k1<<<768, 256, 0, stream>>>(x1, x2, W1, b1, w2, Hb, Gb, Cws);
    ntk_k2<<<256, 512, 0, stream>>>(Hb, Gb, Cws, out);
}

// Round 5
// 22.923 us; speedup vs baseline: 1.8013x; 1.0658x over previous
//
#include <hip/hip_runtime.h>
#include <hip/hip_bf16.h>

#define NS   256
#define DIN  512
#define DHID 1024

typedef __attribute__((ext_vector_type(8)))  short bf16x8;
typedef __attribute__((ext_vector_type(4)))  float f32x4;
typedef __attribute__((ext_vector_type(16))) float f32x16;

static __device__ __forceinline__ short f2bf(float f) {
    return __builtin_bit_cast(short, __float2bfloat16(f));   // RNE
}

static __device__ __forceinline__ bf16x8 cvt8(f32x4 a, f32x4 b) {
    bf16x8 r;
    r[0] = f2bf(a[0]); r[1] = f2bf(a[1]); r[2] = f2bf(a[2]); r[3] = f2bf(a[3]);
    r[4] = f2bf(b[0]); r[5] = f2bf(b[1]); r[6] = f2bf(b[2]); r[7] = f2bf(b[3]);
    return r;
}

// ---------------- K1: heterogeneous, 192 blocks, 32x32x16 MFMA ----------------
// blocks 0..127  : feat. block = 32 rows x 128 cols; wave w = 32x32 tile (cols share
//                  nothing -> expensive strided W1 loads NOT duplicated; A-row loads
//                  duplicated across waves but vectorized/cheap).
//                  Z = X@W1+b1; Hb = relu(Z), Gb = (Z>0)*w2 (bf16).
//                  32x32x16 halves scalar B-loads per MAC vs 16x16x32.
// blocks 128..191: c-gram x1.x2^T -> Cws. 32x32 tile, 4-wave K-split (8 ksteps each).
// Frag layouts (m74/m101): A/B lane l -> row/col = l&31, k = (l>>5)*8 + i.
// D lane l, reg r -> col = l&31, row = (r&3) + 8*(r>>2) + 4*(l>>5).
__global__ __launch_bounds__(256) void ntk_k1(
    const float* __restrict__ x1, const float* __restrict__ x2,
    const float* __restrict__ W1, const float* __restrict__ b1,
    const float* __restrict__ w2,
    short* __restrict__ Hb, short* __restrict__ Gb,
    float* __restrict__ Cws)
{
    const int tid = threadIdx.x;
    const int l   = tid & 63;
    const int w   = tid >> 6;
    const int lc  = l & 31;          // A-row / B-col / D-col
    const int hk  = l >> 5;          // k half-group (0/1)
    const int b   = blockIdx.x;

    __shared__ f32x16 red[4][64];    // 16 KiB (c-gram blocks only)

    if (b < 128) {
        // ---------- feature pass ----------
        const int m0  = (b >> 3) * 32;                 // row tile 0..480
        const int col = (b & 7) * 128 + w * 32 + lc;   // output column
        const float* X  = (m0 < NS) ? (x1 + (size_t)m0 * DIN)
                                    : (x2 + (size_t)(m0 - NS) * DIN);
        const float* ap = X + lc * DIN + hk * 8;
        const float* bp = W1 + (size_t)(hk * 8) * DHID + col;

        f32x16 acc = {};
        #pragma unroll 4
        for (int t = 0; t < 32; ++t) {
            const int k0 = t * 16;
            bf16x8 a = cvt8(*(const f32x4*)(ap + k0), *(const f32x4*)(ap + k0 + 4));
            f32x4 b0v, b1v;
            #pragma unroll
            for (int i = 0; i < 4; ++i) b0v[i] = bp[(size_t)(k0 + i) * DHID];
            #pragma unroll
            for (int i = 0; i < 4; ++i) b1v[i] = bp[(size_t)(k0 + 4 + i) * DHID];
            bf16x8 bf = cvt8(b0v, b1v);
            acc = __builtin_amdgcn_mfma_f32_32x32x16_bf16(a, bf, acc, 0, 0, 0);
        }

        const float bbv = b1[col], wwv = w2[col];
        #pragma unroll
        for (int r = 0; r < 16; ++r) {
            const int row = m0 + (r & 3) + 8 * (r >> 2) + 4 * hk;
            float z = acc[r] + bbv;
            Hb[row * DHID + col] = f2bf(z > 0.f ? z   : 0.f);
            Gb[row * DHID + col] = f2bf(z > 0.f ? wwv : 0.f);
        }
    } else {
        // ---------- c = x1 . x2^T ----------
        const int bb = b - 128;
        const int bi = (bb >> 3) * 32;
        const int bj = (bb & 7) * 32;
        // Both operands row-contiguous: A = x1 rows, B[k][col] = x2[col][k].
        const float* ar = x1 + (bi + lc) * DIN + hk * 8;
        const float* br = x2 + (bj + lc) * DIN + hk * 8;

        f32x16 ac = {};
        #pragma unroll
        for (int q = 0; q < 8; ++q) {                  // 32 ksteps, 4-way wave split
            const int k0 = (w + q * 4) * 16;
            bf16x8 a  = cvt8(*(const f32x4*)(ar + k0), *(const f32x4*)(ar + k0 + 4));
            bf16x8 bv = cvt8(*(const f32x4*)(br + k0), *(const f32x4*)(br + k0 + 4));
            ac = __builtin_amdgcn_mfma_f32_32x32x16_bf16(a, bv, ac, 0, 0, 0);
        }
        red[w][l] = ac;
        __syncthreads();
        if (w == 0) {
            f32x16 c = red[0][l];
            #pragma unroll
            for (int q = 1; q < 4; ++q) c += red[q][l];
            #pragma unroll
            for (int r = 0; r < 16; ++r) {
                const int row = bi + (r & 3) + 8 * (r >> 2) + 4 * hk;
                Cws[row * NS + (bj + lc)] = c[r];
            }
        }
    }
}

// ---------------- K2: g/h grams + combine. 256 blocks x 512 thr ----------------
// out[i][j] = (c + 1) * (g1_i.g2_j) + h1_i.h2_j + 1   (16x16x32, 8-way K-split)
__global__ __launch_bounds__(512) void ntk_k2(
    const short* __restrict__ Hb, const short* __restrict__ Gb,
    const float* __restrict__ Cws, float* __restrict__ out)
{
    const int tid = threadIdx.x;
    const int l   = tid & 63;
    const int w   = tid >> 6;          // 0..7
    const int lr  = l & 15;
    const int kg  = l >> 4;
    const int bi  = (blockIdx.x >> 4) * 16;
    const int bj  = (blockIdx.x & 15) * 16;

    __shared__ f32x4 red[2][8][64];    // 16 KiB

    f32x4 ag = {0.f,0.f,0.f,0.f}, ah = {0.f,0.f,0.f,0.f};

    const short* ga = Gb + (bi + lr) * DHID + kg * 8;
    const short* gb = Gb + (NS + bj + lr) * DHID + kg * 8;
    const short* ha = Hb + (bi + lr) * DHID + kg * 8;
    const short* hb = Hb + (NS + bj + lr) * DHID + kg * 8;

    #pragma unroll
    for (int t = 0; t < 4; ++t) {      // 32 ksteps, 8-way wave split
        const int k = (w + t * 8) * 32;
        bf16x8 a  = *(const bf16x8*)(ga + k);
        bf16x8 bv = *(const bf16x8*)(gb + k);
        ag = __builtin_amdgcn_mfma_f32_16x16x32_bf16(a, bv, ag, 0, 0, 0);
        bf16x8 a2 = *(const bf16x8*)(ha + k);
        bf16x8 b2 = *(const bf16x8*)(hb + k);
        ah = __builtin_amdgcn_mfma_f32_16x16x32_bf16(a2, b2, ah, 0, 0, 0);
    }

    red[0][w][l] = ag; red[1][w][l] = ah;
    __syncthreads();
    if (w == 0) {
        f32x4 g = red[0][0][l], h = red[1][0][l];
        #pragma unroll
        for (int q = 1; q < 8; ++q) { g += red[0][q][l]; h += red[1][q][l]; }
        #pragma unroll
        for (int r = 0; r < 4; ++r) {
            const int idx = (bi + kg * 4 + r) * NS + (bj + lr);
            out[idx] = (Cws[idx] + 1.f) * g[r] + h[r] + 1.f;
        }
    }
}

extern "C" void kernel_launch(void* const* d_in, const int* in_sizes, int n_in,
                              void* d_out, int out_size, void* d_ws, size_t ws_size,
                              hipStream_t stream) {
    const float* x1 = (const float*)d_in[0];   // [256,512]
    const float* x2 = (const float*)d_in[1];   // [256,512]
    const float* W1 = (const float*)d_in[2];   // [512,1024]
    const float* b1 = (const float*)d_in[3];   // [1024]
    const float* w2 = (const float*)d_in[4];   // [1024,1]
    // d_in[5] = b2: d f / d b2 == 1 always -> the "+1" term.

    short* Hb  = (short*)d_ws;                 // [512,1024] bf16, 1 MiB
    short* Gb  = Hb + 2 * NS * DHID;           // [512,1024] bf16, 1 MiB
    float* Cws = (float*)(Gb + 2 * NS * DHID); // [256,256]  f32, 256 KiB
    float* out = (float*)d_out;                // [256,256]

    ntk_k1<<<192, 256, 0, stream>>>(x1, x2, W1, b1, w2, Hb, Gb, Cws);
    ntk_k2<<<256, 512, 0, stream>>>(Hb, Gb, Cws, out);
}